// Round 6
// baseline (222.702 us; speedup 1.0000x reference)
//
#include <hip/hip_runtime.h>

#define NN 8192
#define FIN 512
#define FOUT 256
#define JS 8
#define STRIP 1024   // j per strip
#define NSTEP 32     // 32 j per step

typedef _Float16 f16;
typedef __attribute__((ext_vector_type(8))) _Float16 f16x8;
typedef __attribute__((ext_vector_type(4))) _Float16 f16x4;
typedef __attribute__((ext_vector_type(4))) float f32x4;
typedef __attribute__((ext_vector_type(16))) float f32x16;
typedef __attribute__((ext_vector_type(4))) int i32x4;

__device__ __forceinline__ float lrelu(float x) { return fmaxf(x, 0.2f * x); }

// ---- pack adj (int32 0/1, 256 MiB) -> bitmask (8 MB). Pure streaming at
// HBM BW. word w of row r: bit e = adj[r][32w+e] > 0.
__global__ void k_convert(const int* __restrict__ adj, unsigned* __restrict__ maskG) {
  int id = blockIdx.x * 256 + threadIdx.x;  // 2M threads, one word each
  const int* src = adj + (size_t)id * 32;
  unsigned mword = 0;
#pragma unroll
  for (int q = 0; q < 8; ++q) {
    i32x4 v = __builtin_nontemporal_load((const i32x4*)(src + 4 * q));
#pragma unroll
    for (int e = 0; e < 4; ++e) mword |= (v[e] > 0 ? 1u : 0u) << (4 * q + e);
  }
  maskG[id] = mword;
}

// ---- prep W: f32 [FIN][FOUT] -> f16 hi/lo transposed [FOUT][FIN]
__global__ void k_prep_w(const float* __restrict__ W, f16* __restrict__ wth,
                         f16* __restrict__ wtl) {
  int id = blockIdx.x * 256 + threadIdx.x;
  int c = id >> 9, k = id & 511;
  float v = W[k * FOUT + c];
  f16 a = (f16)v;
  wth[c * FIN + k] = a;
  wtl[c * FIN + k] = (f16)(v - (float)a);
}

// ---- GEMM1: Wh = h @ W via split-f16 MFMA; h converted to hi/lo in-reg.
// Emits whT16 (f16, tiled [j/16][256 c][16 j]), Wh1, Wh2 (f32).
__launch_bounds__(256, 2)
__global__ void k_gemm1(const float* __restrict__ h, const f16* __restrict__ wth,
                        const f16* __restrict__ wtl, const float* __restrict__ avec,
                        f16* __restrict__ whT16, float* __restrict__ wh1,
                        float* __restrict__ wh2) {
  int i0 = blockIdx.x * 32;
  int tid = threadIdx.x;
  int w = tid >> 6, l = tid & 63, m = l & 15, g = l >> 4;
  f32x4 acc[2][4] = {};
#pragma unroll 1
  for (int k0 = 0; k0 < FIN; k0 += 32) {
    f16x8 ah[2], al[2], bh[4], bl[4];
#pragma unroll
    for (int rf = 0; rf < 2; ++rf) {
      int ro = (i0 + 16 * rf + m) * FIN + k0 + 8 * g;
      f32x4 va = *(const f32x4*)(h + ro);
      f32x4 vb = *(const f32x4*)(h + ro + 4);
#pragma unroll
      for (int e = 0; e < 4; ++e) {
        f16 x = (f16)va[e];
        ah[rf][e] = x;
        al[rf][e] = (f16)(va[e] - (float)x);
        f16 y = (f16)vb[e];
        ah[rf][4 + e] = y;
        al[rf][4 + e] = (f16)(vb[e] - (float)y);
      }
    }
#pragma unroll
    for (int cf = 0; cf < 4; ++cf) {
      int co = (64 * w + 16 * cf + m) * FIN + k0 + 8 * g;
      bh[cf] = *(const f16x8*)(wth + co);
      bl[cf] = *(const f16x8*)(wtl + co);
    }
#pragma unroll
    for (int rf = 0; rf < 2; ++rf)
#pragma unroll
      for (int cf = 0; cf < 4; ++cf) {
        acc[rf][cf] = __builtin_amdgcn_mfma_f32_16x16x32_f16(ah[rf], bh[cf], acc[rf][cf], 0, 0, 0);
        acc[rf][cf] = __builtin_amdgcn_mfma_f32_16x16x32_f16(ah[rf], bl[cf], acc[rf][cf], 0, 0, 0);
        acc[rf][cf] = __builtin_amdgcn_mfma_f32_16x16x32_f16(al[rf], bh[cf], acc[rf][cf], 0, 0, 0);
      }
  }
  __shared__ float tile[32][FOUT + 1];
#pragma unroll
  for (int rf = 0; rf < 2; ++rf)
#pragma unroll
    for (int cf = 0; cf < 4; ++cf)
#pragma unroll
      for (int r = 0; r < 4; ++r)
        tile[16 * rf + 4 * g + r][64 * w + 16 * cf + m] = acc[rf][cf][r];
  __syncthreads();
  {  // whT16 tiled write: thread = column c, 32 rows = 2 j16-groups
    int c = tid;
    f16x8 vv[4];
#pragma unroll
    for (int r = 0; r < 32; ++r) vv[r >> 3][r & 7] = (f16)tile[r][c];
    size_t base = ((size_t)(i0 >> 4) * 256 + c) * 16;
    *(f16x8*)(whT16 + base) = vv[0];
    *(f16x8*)(whT16 + base + 8) = vv[1];
    *(f16x8*)(whT16 + base + 4096) = vv[2];
    *(f16x8*)(whT16 + base + 4096 + 8) = vv[3];
  }
  {  // Wh1/Wh2 row dots: 8 lanes per row
    int r = tid >> 3, ls = tid & 7;
    float s1 = 0.f, s2 = 0.f;
    for (int c = ls; c < FOUT; c += 8) {
      float v = tile[r][c];
      s1 = fmaf(v, avec[c], s1);
      s2 = fmaf(v, avec[FOUT + c], s2);
    }
#pragma unroll
    for (int off = 1; off < 8; off <<= 1) {
      s1 += __shfl_xor(s1, off);
      s2 += __shfl_xor(s2, off);
    }
    if (ls == 0) {
      wh1[i0 + r] = s1;
      wh2[i0 + r] = s2;
    }
  }
}

// ---- global max of Wh2 (safe softmax shift bound)
__global__ void k_max2(const float* __restrict__ wh2, float* __restrict__ m2) {
  int t = threadIdx.x;
  float mx = -1e30f;
  for (int i = t; i < NN; i += 256) mx = fmaxf(mx, wh2[i]);
#pragma unroll
  for (int off = 1; off < 64; off <<= 1) mx = fmaxf(mx, __shfl_xor(mx, off));
  __shared__ float sm[4];
  if ((t & 63) == 0) sm[t >> 6] = mx;
  __syncthreads();
  if (t == 0) m2[0] = fmaxf(fmaxf(sm[0], sm[1]), fmaxf(sm[2], sm[3]));
}

// ---- fused masked-softmax + PV. Barrier-free; mask bits from LDS (staged
// wave-privately once); only w2 (L1) and B (L2) global loads in the loop.
// Grid: rb(32) x js(8, XCD-affine) x cs(2). Block: 4 waves; wave = 64 rows
// (2 rg) x 128 cols x 1024-j strip. Lane: lr=l&31 (A-row), hi=l>>5 (k-half).
// acc[2][4] f32x16 = 128 AGPR.
__launch_bounds__(256, 2)
__global__ void k_attn(const unsigned* __restrict__ maskG, const f16* __restrict__ whT16,
                       const float* __restrict__ wh1, const float* __restrict__ wh2,
                       const float* __restrict__ m2g, f16* __restrict__ accP,
                       float* __restrict__ zP) {
  int bx = blockIdx.x;
  int js = bx & 7, cs = (bx >> 3) & 1, rb = bx >> 4;
  int i0b = rb * 256;
  int jbase = js * STRIP;
  int tid = threadIdx.x, w = tid >> 6, l = tid & 63;
  int lr = l & 31, hi = l >> 5;
  int r0 = i0b + w * 64 + lr;  // rg0 row; rg1 = r0 + 32

  // stage this wave's 64 mask rows (32 words each) into LDS; wave-private,
  // in-order DS => no barrier needed anywhere.
  __shared__ unsigned maskL[4][64][36];  // pad 36 (16B-aligned rows)
  {
    const unsigned* ms = maskG + (size_t)(i0b + w * 64 + l) * 256 + js * 32;
#pragma unroll
    for (int q = 0; q < 8; ++q)
      *(i32x4*)(&maskL[w][l][4 * q]) = *(const i32x4*)(ms + 4 * q);
  }

  float M2 = m2g[0];
  float w1a = wh1[r0], w1b = wh1[r0 + 32];
  float mra = lrelu(w1a + M2), mrb = lrelu(w1b + M2);

  f32x16 acc[2][4] = {};
  float za = 0.f, zb = 0.f;

  const size_t jb16 = (size_t)(jbase >> 4) * 256 * 16;
  const f16* bPB = whT16 + jb16 + (size_t)(cs * 128 + lr) * 16 + hi * 8;
  const float* w2b = wh2 + jbase + 8 * hi;

  // B software pipeline: bfA holds (t, kb=0); loaded one kb-phase ahead.
  f16x8 bfA[4], bfB[4];
#pragma unroll
  for (int c = 0; c < 4; ++c)
    bfA[c] = *(const f16x8*)(bPB + ((size_t)c * 32) * 16);

#pragma unroll 1
  for (int t = 0; t < NSTEP; ++t) {
    int jc = t * 32;
    // mask words for both row-groups (LDS, 2-way/4-way aliasing only)
    unsigned mw0 = maskL[w][lr][t];
    unsigned mw1 = maskL[w][32 + lr][t];
    // w2 for this step's two k-blocks (L1-resident strip)
    f32x4 wv00 = *(const f32x4*)(w2b + jc);
    f32x4 wv01 = *(const f32x4*)(w2b + jc + 4);
    f32x4 wv10 = *(const f32x4*)(w2b + jc + 16);
    f32x4 wv11 = *(const f32x4*)(w2b + jc + 20);
    // genP: pa{rg}{kb}[f] = P[row_rg][jc + 16kb + 8hi + f]
    f16x8 pa00, pa01, pa10, pa11;
#pragma unroll
    for (int f = 0; f < 8; ++f) {
      float w2k0 = (f < 4) ? wv00[f & 3] : wv01[f & 3];
      float w2k1 = (f < 4) ? wv10[f & 3] : wv11[f & 3];
      int b0 = 8 * hi + f, b1 = 16 + 8 * hi + f;
      // rg0
      float s0 = w1a + w2k0;
      float p0 = ((mw0 >> b0) & 1u) ? __expf(fmaxf(s0, 0.2f * s0) - mra) : 0.f;
      float s1 = w1a + w2k1;
      float p1 = ((mw0 >> b1) & 1u) ? __expf(fmaxf(s1, 0.2f * s1) - mra) : 0.f;
      za += p0 + p1;
      pa00[f] = (f16)p0;
      pa01[f] = (f16)p1;
      // rg1
      float s2 = w1b + w2k0;
      float p2 = ((mw1 >> b0) & 1u) ? __expf(fmaxf(s2, 0.2f * s2) - mrb) : 0.f;
      float s3 = w1b + w2k1;
      float p3 = ((mw1 >> b1) & 1u) ? __expf(fmaxf(s3, 0.2f * s3) - mrb) : 0.f;
      zb += p2 + p3;
      pa10[f] = (f16)p2;
      pa11[f] = (f16)p3;
    }
    // kb=0: issue kb=1 loads, MFMA with bfA
    {
      const f16* bk = bPB + ((size_t)(2 * t + 1) * 256) * 16;
#pragma unroll
      for (int c = 0; c < 4; ++c)
        bfB[c] = *(const f16x8*)(bk + ((size_t)c * 32) * 16);
#pragma unroll
      for (int c = 0; c < 4; ++c) {
        acc[0][c] = __builtin_amdgcn_mfma_f32_32x32x16_f16(pa00, bfA[c], acc[0][c], 0, 0, 0);
        acc[1][c] = __builtin_amdgcn_mfma_f32_32x32x16_f16(pa10, bfA[c], acc[1][c], 0, 0, 0);
      }
    }
    // kb=1: issue next step's kb=0 loads, MFMA with bfB
    {
      int tn = (t + 1 < NSTEP) ? t + 1 : t;
      const f16* bk = bPB + ((size_t)(2 * tn) * 256) * 16;
#pragma unroll
      for (int c = 0; c < 4; ++c)
        bfA[c] = *(const f16x8*)(bk + ((size_t)c * 32) * 16);
#pragma unroll
      for (int c = 0; c < 4; ++c) {
        acc[0][c] = __builtin_amdgcn_mfma_f32_32x32x16_f16(pa01, bfB[c], acc[0][c], 0, 0, 0);
        acc[1][c] = __builtin_amdgcn_mfma_f32_32x32x16_f16(pa11, bfB[c], acc[1][c], 0, 0, 0);
      }
    }
  }

  // Z: hi=0/1 lanes hold complementary j-halves of each row
  za += __shfl_xor(za, 32);
  zb += __shfl_xor(zb, 32);
  if (hi == 0 && cs == 0) {
    zP[(size_t)js * NN + r0] = za;
    zP[(size_t)js * NN + r0 + 32] = zb;
  }

  // partial accumulator out, f16 NT. C/D: col=lane&31, row=(r&3)+8*(r>>2)+4*hi
  f16* ap = accP + (size_t)js * NN * FOUT;
#pragma unroll
  for (int rg = 0; rg < 2; ++rg)
#pragma unroll
    for (int cf = 0; cf < 4; ++cf)
#pragma unroll
      for (int r = 0; r < 16; ++r) {
        int grow = i0b + w * 64 + rg * 32 + (r & 3) + 8 * (r >> 2) + 4 * hi;
        int gcol = cs * 128 + cf * 32 + lr;
        __builtin_nontemporal_store((f16)acc[rg][cf][r], ap + (size_t)grow * FOUT + gcol);
      }
}

// ---- combine JS f16 partials, divide by Z, elu
__global__ void k_combine(const f16* __restrict__ accP, const float* __restrict__ zP,
                          float* __restrict__ out) {
  int id = blockIdx.x * 256 + threadIdx.x;
  size_t idx = (size_t)id * 4;
  int row = (int)(idx >> 8);
  f32x4 s = {};
#pragma unroll
  for (int p = 0; p < JS; ++p) {
    f16x4 v = *(const f16x4*)(accP + (size_t)p * NN * FOUT + idx);
#pragma unroll
    for (int i = 0; i < 4; ++i) s[i] += (float)v[i];
  }
  float z = 0.f;
#pragma unroll
  for (int p = 0; p < JS; ++p) z += zP[(size_t)p * NN + row];
  float inv = (z > 0.f) ? 1.f / z : 0.f;
  f32x4 o;
#pragma unroll
  for (int i = 0; i < 4; ++i) {
    float x = s[i] * inv;
    o[i] = (x > 0.f) ? x : expm1f(x);
  }
  *(f32x4*)(out + idx) = o;
}

extern "C" void kernel_launch(void* const* d_in, const int* in_sizes, int n_in,
                              void* d_out, int out_size, void* d_ws, size_t ws_size,
                              hipStream_t stream) {
  const float* h = (const float*)d_in[0];
  const int* adj = (const int*)d_in[1];
  const float* W = (const float*)d_in[2];
  const float* a = (const float*)d_in[3];
  (void)in_sizes; (void)n_in; (void)out_size; (void)ws_size;

  char* ws = (char*)d_ws;
  size_t off = 0;
  auto alloc = [&](size_t bytes) {
    void* p = ws + off;
    off = (off + bytes + 255) & ~(size_t)255;
    return p;
  };
  f16* accP = (f16*)alloc((size_t)JS * NN * FOUT * 2);      // 32 MB
  f16* whT16 = (f16*)alloc((size_t)FOUT * NN * 2);          // 4 MB
  unsigned* maskG = (unsigned*)alloc((size_t)NN * 256 * 4); // 8 MB
  f16* wth = (f16*)alloc((size_t)FOUT * FIN * 2);
  f16* wtl = (f16*)alloc((size_t)FOUT * FIN * 2);
  float* wh1 = (float*)alloc((size_t)NN * 4);
  float* wh2 = (float*)alloc((size_t)NN * 4);
  float* m2 = (float*)alloc(256);
  float* zP = (float*)alloc((size_t)JS * NN * 4);

  k_convert<<<NN * NN / 32 / 256, 256, 0, stream>>>(adj, maskG);
  k_prep_w<<<FIN * FOUT / 256, 256, 0, stream>>>(W, wth, wtl);
  k_gemm1<<<NN / 32, 256, 0, stream>>>(h, wth, wtl, a, whT16, wh1, wh2);
  k_max2<<<1, 256, 0, stream>>>(wh2, m2);
  k_attn<<<32 * JS * 2, 256, 0, stream>>>(maskG, whT16, wh1, wh2, m2, accP, zP);
  k_combine<<<NN * FOUT / 1024, 256, 0, stream>>>(accP, zP, (float*)d_out);
}

// Round 7
// 156.011 us; speedup vs baseline: 1.4275x; 1.4275x over previous
//
#include <hip/hip_runtime.h>

#define NN 8192
#define FIN 512
#define FOUT 256
#define JS 8
#define STRIP 1024   // j per strip
#define NSTEP 32     // 32 j per step

typedef _Float16 f16;
typedef __attribute__((ext_vector_type(8))) _Float16 f16x8;
typedef __attribute__((ext_vector_type(4))) _Float16 f16x4;
typedef __attribute__((ext_vector_type(4))) float f32x4;
typedef __attribute__((ext_vector_type(16))) float f32x16;
typedef __attribute__((ext_vector_type(4))) int i32x4;
typedef unsigned long long u64;

__device__ __forceinline__ float lrelu(float x) { return fmaxf(x, 0.2f * x); }

// ---- pack adj -> bitmask via ballot. Wave = one adj row (32 KB, 32 fully
// coalesced 1KB passes). Layout: maskG[row*128 + pass*4 + e], bit l of word
// e <-> j = pass*256 + 4*l + e.
__global__ void k_convert(const int* __restrict__ adj, u64* __restrict__ maskG) {
  int gw = blockIdx.x * 4 + (threadIdx.x >> 6);  // wave id == row
  int l = threadIdx.x & 63;
  const int* src = adj + (size_t)gw * NN + 4 * l;
  u64* dst = maskG + (size_t)gw * 128;
#pragma unroll 1
  for (int p = 0; p < 32; ++p) {
    i32x4 v = __builtin_nontemporal_load((const i32x4*)(src + p * 256));
    u64 b0 = __ballot(v[0] > 0);
    u64 b1 = __ballot(v[1] > 0);
    u64 b2 = __ballot(v[2] > 0);
    u64 b3 = __ballot(v[3] > 0);
    if (l < 4) {
      u64 bb = (l == 0) ? b0 : (l == 1) ? b1 : (l == 2) ? b2 : b3;
      dst[p * 4 + l] = bb;
    }
  }
}

// ---- prep W: f32 [FIN][FOUT] -> f16 hi/lo transposed [FOUT][FIN]
__global__ void k_prep_w(const float* __restrict__ W, f16* __restrict__ wth,
                         f16* __restrict__ wtl) {
  int id = blockIdx.x * 256 + threadIdx.x;
  int c = id >> 9, k = id & 511;
  float v = W[k * FOUT + c];
  f16 a = (f16)v;
  wth[c * FIN + k] = a;
  wtl[c * FIN + k] = (f16)(v - (float)a);
}

// ---- GEMM1: Wh = h @ W via split-f16 MFMA; h converted to hi/lo in-reg.
// Emits whT16 (f16, tiled [j/16][256 c][16 j]), Wh1, Wh2 (f32).
__launch_bounds__(256, 2)
__global__ void k_gemm1(const float* __restrict__ h, const f16* __restrict__ wth,
                        const f16* __restrict__ wtl, const float* __restrict__ avec,
                        f16* __restrict__ whT16, float* __restrict__ wh1,
                        float* __restrict__ wh2) {
  int i0 = blockIdx.x * 32;
  int tid = threadIdx.x;
  int w = tid >> 6, l = tid & 63, m = l & 15, g = l >> 4;
  f32x4 acc[2][4] = {};
#pragma unroll 1
  for (int k0 = 0; k0 < FIN; k0 += 32) {
    f16x8 ah[2], al[2], bh[4], bl[4];
#pragma unroll
    for (int rf = 0; rf < 2; ++rf) {
      int ro = (i0 + 16 * rf + m) * FIN + k0 + 8 * g;
      f32x4 va = *(const f32x4*)(h + ro);
      f32x4 vb = *(const f32x4*)(h + ro + 4);
#pragma unroll
      for (int e = 0; e < 4; ++e) {
        f16 x = (f16)va[e];
        ah[rf][e] = x;
        al[rf][e] = (f16)(va[e] - (float)x);
        f16 y = (f16)vb[e];
        ah[rf][4 + e] = y;
        al[rf][4 + e] = (f16)(vb[e] - (float)y);
      }
    }
#pragma unroll
    for (int cf = 0; cf < 4; ++cf) {
      int co = (64 * w + 16 * cf + m) * FIN + k0 + 8 * g;
      bh[cf] = *(const f16x8*)(wth + co);
      bl[cf] = *(const f16x8*)(wtl + co);
    }
#pragma unroll
    for (int rf = 0; rf < 2; ++rf)
#pragma unroll
      for (int cf = 0; cf < 4; ++cf) {
        acc[rf][cf] = __builtin_amdgcn_mfma_f32_16x16x32_f16(ah[rf], bh[cf], acc[rf][cf], 0, 0, 0);
        acc[rf][cf] = __builtin_amdgcn_mfma_f32_16x16x32_f16(ah[rf], bl[cf], acc[rf][cf], 0, 0, 0);
        acc[rf][cf] = __builtin_amdgcn_mfma_f32_16x16x32_f16(al[rf], bh[cf], acc[rf][cf], 0, 0, 0);
      }
  }
  __shared__ float tile[32][FOUT + 1];
#pragma unroll
  for (int rf = 0; rf < 2; ++rf)
#pragma unroll
    for (int cf = 0; cf < 4; ++cf)
#pragma unroll
      for (int r = 0; r < 4; ++r)
        tile[16 * rf + 4 * g + r][64 * w + 16 * cf + m] = acc[rf][cf][r];
  __syncthreads();
  {  // whT16 tiled write: thread = column c, 32 rows = 2 j16-groups
    int c = tid;
    f16x8 vv[4];
#pragma unroll
    for (int r = 0; r < 32; ++r) vv[r >> 3][r & 7] = (f16)tile[r][c];
    size_t base = ((size_t)(i0 >> 4) * 256 + c) * 16;
    *(f16x8*)(whT16 + base) = vv[0];
    *(f16x8*)(whT16 + base + 8) = vv[1];
    *(f16x8*)(whT16 + base + 4096) = vv[2];
    *(f16x8*)(whT16 + base + 4096 + 8) = vv[3];
  }
  {  // Wh1/Wh2 row dots: 8 lanes per row
    int r = tid >> 3, ls = tid & 7;
    float s1 = 0.f, s2 = 0.f;
    for (int c = ls; c < FOUT; c += 8) {
      float v = tile[r][c];
      s1 = fmaf(v, avec[c], s1);
      s2 = fmaf(v, avec[FOUT + c], s2);
    }
#pragma unroll
    for (int off = 1; off < 8; off <<= 1) {
      s1 += __shfl_xor(s1, off);
      s2 += __shfl_xor(s2, off);
    }
    if (ls == 0) {
      wh1[i0 + r] = s1;
      wh2[i0 + r] = s2;
    }
  }
}

// ---- global max of Wh2 (safe softmax shift bound)
__global__ void k_max2(const float* __restrict__ wh2, float* __restrict__ m2) {
  int t = threadIdx.x;
  float mx = -1e30f;
  for (int i = t; i < NN; i += 256) mx = fmaxf(mx, wh2[i]);
#pragma unroll
  for (int off = 1; off < 64; off <<= 1) mx = fmaxf(mx, __shfl_xor(mx, off));
  __shared__ float sm[4];
  if ((t & 63) == 0) sm[t >> 6] = mx;
  __syncthreads();
  if (t == 0) m2[0] = fmaxf(fmaxf(sm[0], sm[1]), fmaxf(sm[2], sm[3]));
}

// ---- per-row/per-col exp factor tables (exp-free genP in k_attn):
// pos branch: p = E1p_i * E2p_j ; neg branch: p = E1n_i * E2n_j ;
// branch select: E2p_j >= T_i  <=>  w1_i + w2_j >= 0.
__global__ void k_prep2(const float* __restrict__ wh1, const float* __restrict__ wh2,
                        const float* __restrict__ m2g, float* __restrict__ e1p,
                        float* __restrict__ e1n, float* __restrict__ thr,
                        float* __restrict__ e2p, float* __restrict__ e2n) {
  int i = blockIdx.x * 256 + threadIdx.x;
  const float L = 1.4426950408889634f;
  float M2 = m2g[0];
  float w1 = wh1[i], w2 = wh2[i];
  float m = lrelu(w1 + M2);
  e1p[i] = exp2f((w1 - m) * L);
  e1n[i] = exp2f((0.2f * w1 - m) * L);
  thr[i] = exp2f(-w1 * L);
  e2p[i] = exp2f(w2 * L);
  e2n[i] = exp2f(0.2f * w2 * L);
}

// ---- fused masked-softmax + PV. Barrier-free, exp-free. Grid: 64rb x 8js
// (js=bx&7 -> XCD-affine whT16 strip). Block: 4 waves; wave = 32 rows x
// 1024-j strip x 256 cols. acc[8] f32x16 = 128 AGPR. Mask bits from
// wave-private LDS (staged once, ballot layout). B double-banked with
// ~full-step issue lead.
__launch_bounds__(256, 2)
__global__ void k_attn(const u64* __restrict__ maskG, const f16* __restrict__ whT16,
                       const float* __restrict__ e1pA, const float* __restrict__ e1nA,
                       const float* __restrict__ thrA, const float* __restrict__ e2pA,
                       const float* __restrict__ e2nA, f16* __restrict__ accP,
                       float* __restrict__ zP) {
  int bx = blockIdx.x;
  int js = bx & (JS - 1), rb = bx >> 3;
  int i0b = rb * 128;
  int jbase = js * STRIP;
  int tid = threadIdx.x, w = tid >> 6, l = tid & 63;
  int lr = l & 31, hi = l >> 5;
  int row = i0b + w * 32 + lr;

  // stage this wave's 32 rows x 16 mask words (pad row to 18 u64 = 144 B)
  __shared__ u64 mrow[4][32][18];
#pragma unroll
  for (int p = 0; p < 4; ++p) {
    int r = 8 * p + (l >> 3);
    const i32x4* src =
        (const i32x4*)(maskG + (size_t)(i0b + 32 * w + r) * 128 + js * 16) + (l & 7);
    *(i32x4*)(&mrow[w][r][(l & 7) * 2]) = *src;
  }
  // wave-private + DS in-order => no barrier

  float E1p = e1pA[row], E1n = e1nA[row], T = thrA[row];
  f32x16 acc[8] = {};
  float za = 0.f;

  const f16* bPB = whT16 + ((size_t)(jbase >> 4)) * 256 * 16 + (size_t)lr * 16 + hi * 8;
  const float* e2pb = e2pA + jbase + 8 * hi;
  const float* e2nb = e2nA + jbase + 8 * hi;

  f16x8 bfA[8], bfB[8];
#pragma unroll
  for (int c = 0; c < 8; ++c) bfA[c] = *(const f16x8*)(bPB + c * 512);

#pragma unroll 1
  for (int ch = 0; ch < 4; ++ch) {
    u64 wreg[4];
#pragma unroll
    for (int q = 0; q < 4; ++q) wreg[q] = mrow[w][lr][ch * 4 + q];
#pragma unroll 1
    for (int ts = 0; ts < 8; ++ts) {
      int t = ch * 8 + ts;
      int jc = t * 32;
      // issue B(t, kb1) early (lead ~= genP + kb0-MFMA)
      {
        const f16* bt = bPB + (size_t)(2 * t + 1) * 4096;
#pragma unroll
        for (int c = 0; c < 8; ++c) bfB[c] = *(const f16x8*)(bt + c * 512);
      }
      // genP: bit l of chunk word e <-> j = chunk*256 + 4l + e
      int sb = ts * 8 + 2 * hi;
      unsigned b4[4];
#pragma unroll
      for (int e = 0; e < 4; ++e) b4[e] = (unsigned)(wreg[e] >> sb);
      f16x8 pa0, pa1;
#pragma unroll
      for (int q = 0; q < 2; ++q) {
        int fo = jc + 4 * q;
        f32x4 ep0 = *(const f32x4*)(e2pb + fo);
        f32x4 en0 = *(const f32x4*)(e2nb + fo);
        f32x4 ep1 = *(const f32x4*)(e2pb + fo + 16);
        f32x4 en1 = *(const f32x4*)(e2nb + fo + 16);
#pragma unroll
        for (int e = 0; e < 4; ++e) {
          int f = 4 * q + e;
          bool s0 = ep0[e] >= T;
          float pv0 = (s0 ? E1p : E1n) * (s0 ? ep0[e] : en0[e]);
          pv0 = ((b4[e] >> q) & 1u) ? pv0 : 0.f;
          za += pv0;
          pa0[f] = (f16)pv0;
          bool s1 = ep1[e] >= T;
          float pv1 = (s1 ? E1p : E1n) * (s1 ? ep1[e] : en1[e]);
          pv1 = ((b4[e] >> (4 + q)) & 1u) ? pv1 : 0.f;
          za += pv1;
          pa1[f] = (f16)pv1;
        }
      }
      // kb0 MFMA (bfA loaded one phase ago)
#pragma unroll
      for (int c = 0; c < 8; ++c)
        acc[c] = __builtin_amdgcn_mfma_f32_32x32x16_f16(pa0, bfA[c], acc[c], 0, 0, 0);
      // issue B(t+1, kb0) (lead ~= kb1-MFMA + next genP)
      {
        int tn = (t + 1 < NSTEP) ? t + 1 : t;
        const f16* bt = bPB + (size_t)(2 * tn) * 4096;
#pragma unroll
        for (int c = 0; c < 8; ++c) bfA[c] = *(const f16x8*)(bt + c * 512);
      }
      // kb1 MFMA
#pragma unroll
      for (int c = 0; c < 8; ++c)
        acc[c] = __builtin_amdgcn_mfma_f32_32x32x16_f16(pa1, bfB[c], acc[c], 0, 0, 0);
    }
  }

  // Z: hi=0/1 lanes hold complementary j-slots of row
  za += __shfl_xor(za, 32);
  if (hi == 0) zP[(size_t)js * NN + row] = za;

  // partial accumulator out, f16 NT. C/D: col=lane&31, row=(r&3)+8*(r>>2)+4*hi
  f16* ap = accP + (size_t)js * NN * FOUT;
#pragma unroll
  for (int c = 0; c < 8; ++c)
#pragma unroll
    for (int r = 0; r < 16; ++r) {
      int grow = i0b + 32 * w + (r & 3) + 8 * (r >> 2) + 4 * hi;
      int gcol = c * 32 + lr;
      __builtin_nontemporal_store((f16)acc[c][r], ap + (size_t)grow * FOUT + gcol);
    }
}

// ---- combine JS f16 partials, divide by Z, elu
__global__ void k_combine(const f16* __restrict__ accP, const float* __restrict__ zP,
                          float* __restrict__ out) {
  int id = blockIdx.x * 256 + threadIdx.x;
  size_t idx = (size_t)id * 4;
  int row = (int)(idx >> 8);
  f32x4 s = {};
#pragma unroll
  for (int p = 0; p < JS; ++p) {
    f16x4 v = *(const f16x4*)(accP + (size_t)p * NN * FOUT + idx);
#pragma unroll
    for (int i = 0; i < 4; ++i) s[i] += (float)v[i];
  }
  float z = 0.f;
#pragma unroll
  for (int p = 0; p < JS; ++p) z += zP[(size_t)p * NN + row];
  float inv = (z > 0.f) ? 1.f / z : 0.f;
  f32x4 o;
#pragma unroll
  for (int i = 0; i < 4; ++i) {
    float x = s[i] * inv;
    o[i] = (x > 0.f) ? x : expm1f(x);
  }
  *(f32x4*)(out + idx) = o;
}

extern "C" void kernel_launch(void* const* d_in, const int* in_sizes, int n_in,
                              void* d_out, int out_size, void* d_ws, size_t ws_size,
                              hipStream_t stream) {
  const float* h = (const float*)d_in[0];
  const int* adj = (const int*)d_in[1];
  const float* W = (const float*)d_in[2];
  const float* a = (const float*)d_in[3];
  (void)in_sizes; (void)n_in; (void)out_size; (void)ws_size;

  char* ws = (char*)d_ws;
  size_t off = 0;
  auto alloc = [&](size_t bytes) {
    void* p = ws + off;
    off = (off + bytes + 255) & ~(size_t)255;
    return p;
  };
  f16* accP = (f16*)alloc((size_t)JS * NN * FOUT * 2);   // 32 MB
  u64* maskG = (u64*)alloc((size_t)NN * 128 * 8);        // 8 MB
  f16* whT16 = (f16*)alloc((size_t)FOUT * NN * 2);       // 4 MB
  f16* wth = (f16*)alloc((size_t)FOUT * FIN * 2);
  f16* wtl = (f16*)alloc((size_t)FOUT * FIN * 2);
  float* wh1 = (float*)alloc((size_t)NN * 4);
  float* wh2 = (float*)alloc((size_t)NN * 4);
  float* m2 = (float*)alloc(256);
  float* e1p = (float*)alloc((size_t)NN * 4);
  float* e1n = (float*)alloc((size_t)NN * 4);
  float* thr = (float*)alloc((size_t)NN * 4);
  float* e2p = (float*)alloc((size_t)NN * 4);
  float* e2n = (float*)alloc((size_t)NN * 4);
  float* zP = (float*)alloc((size_t)JS * NN * 4);

  k_convert<<<NN / 4, 256, 0, stream>>>(adj, maskG);
  k_prep_w<<<FIN * FOUT / 256, 256, 0, stream>>>(W, wth, wtl);
  k_gemm1<<<NN / 32, 256, 0, stream>>>(h, wth, wtl, a, whT16, wh1, wh2);
  k_max2<<<1, 256, 0, stream>>>(wh2, m2);
  k_prep2<<<NN / 256, 256, 0, stream>>>(wh1, wh2, m2, e1p, e1n, thr, e2p, e2n);
  k_attn<<<(NN / 128) * JS, 256, 0, stream>>>(maskG, whT16, e1p, e1n, thr, e2p, e2n,
                                              accP, zP);
  k_combine<<<NN * FOUT / 1024, 256, 0, stream>>>(accP, zP, (float*)d_out);
}